// Round 6
// baseline (121.771 us; speedup 1.0000x reference)
//
#include <hip/hip_runtime.h>

typedef unsigned long long u64;
typedef unsigned int u32;
typedef _Float16 f16;

#define NN 50000
#define NE 600000
#define D  128
#define NWAVE 3125        // 50000 / 16 rows per GEMM wave
#define GGEMM 782         // ceil(3125 / 4 waves per block)
#define EPB 2048          // edges per partition-pass block (8 per thread)
#define NB_P 293          // ceil(600000 / 2048)
#define NP 196            // partitions: col >> 8 (256 nodes each)
#define NSTRIP 4          // hop strips: 32 fp16 cols = 64B; 3.2MB fits XCD L2
#define NCHUNK 782        // node chunks of 64: ceil(50000/64)
#define GHOP 3128         // 8 * 391: xcd x%8 -> strip x>>1, chunk parity x&1

typedef __attribute__((ext_vector_type(8))) __bf16 bf16x8;
typedef __attribute__((ext_vector_type(8))) unsigned short us8;
typedef __attribute__((ext_vector_type(8))) f16 f16x8;
typedef __attribute__((ext_vector_type(4))) float f32x4;

__device__ __forceinline__ unsigned short f2bf(float f) {
    u32 u = __float_as_uint(f);
    return (unsigned short)((u + 0x7FFFu + ((u >> 16) & 1u)) >> 16);  // RNE
}
__device__ __forceinline__ float bf2f(unsigned short h) {
    return __uint_as_float((u32)h << 16);
}

// ---------------------------------------------------------------------------
// prep: pre-convert W into frag-order split-bf16 tables (2048 chunks).
// ---------------------------------------------------------------------------
__global__ __launch_bounds__(256) void wprep(const float* __restrict__ W,
                                             us8* __restrict__ Whi,
                                             us8* __restrict__ Wlo) {
    const int i = blockIdx.x * 256 + threadIdx.x;
    if (i < 2048) {
        const int lane = i & 63, nt = (i >> 6) & 7, kc4 = i >> 9;
        const float* p =
            W + (size_t)(nt * 16 + (lane & 15)) * D + kc4 * 32 + (lane >> 4) * 8;
        float v[8];
        *(float4*)&v[0] = *(const float4*)p;
        *(float4*)&v[4] = *(const float4*)(p + 4);
        us8 hi, lo;
#pragma unroll
        for (int j = 0; j < 8; ++j) {
            const unsigned short hb = f2bf(v[j]);
            hi[j] = hb;
            lo[j] = f2bf(v[j] - bf2f(hb));
        }
        Whi[i] = hi;
        Wlo[i] = lo;
    }
}

// ---------------------------------------------------------------------------
// Fused kernel. Blocks [0, NB_P): partition COUNT — per-block 196-bin LDS
//   histogram of col>>8; writes cnt[p][b] (fully overwrites -> no memset).
// Blocks [NB_P, ...): GEMM h16 = fp16(x @ W^T), split-bf16 MFMA, output
//   fp16 strip-major [4][NN][32].
// ---------------------------------------------------------------------------
__global__ __launch_bounds__(256) void gemm_count(
    const float* __restrict__ x, const us8* __restrict__ Whi,
    const us8* __restrict__ Wlo, f16* __restrict__ h16,
    const int* __restrict__ col, int* __restrict__ cnt) {
    const int t = threadIdx.x;
    __shared__ us8 WH[2048];  // 32 KB (GEMM role); reused as bins (count role)

    if (blockIdx.x < NB_P) {
        // ---- partition-count role ----
        int* bins = (int*)WH;
        for (int i = t; i < NP; i += 256) bins[i] = 0;
        __syncthreads();
        const int e0 = blockIdx.x * EPB + t;
#pragma unroll
        for (int s = 0; s < 8; ++s) {
            const int e = e0 + s * 256;
            if (e < NE) atomicAdd(&bins[col[e] >> 8], 1);
        }
        __syncthreads();
        for (int i = t; i < NP; i += 256)
            cnt[i * NB_P + blockIdx.x] = bins[i];
        return;
    }

    // ---- GEMM role ----
    const int g = (blockIdx.x - NB_P) * 4 + (t >> 6);
    const int lane = t & 63;
    const int gc = (g < NWAVE) ? g : (NWAVE - 1);
    const int row0 = gc * 16;

    // issue all 8 cold x loads up front (128B/lane, 16 full lines per wave)
    const float* px = x + (size_t)(row0 + (lane & 15)) * D + (lane >> 4) * 8;
    float4 ar[8];
#pragma unroll
    for (int c = 0; c < 4; ++c) {
        ar[2 * c]     = *(const float4*)(px + c * 32);
        ar[2 * c + 1] = *(const float4*)(px + c * 32 + 4);
    }

    // stage Whi -> LDS (32 KB, coalesced) while x loads are in flight
#pragma unroll
    for (int i = 0; i < 8; ++i) WH[t + i * 256] = Whi[t + i * 256];
    __syncthreads();
    if (g >= NWAVE) return;

    f32x4 acc[8];
#pragma unroll
    for (int nt = 0; nt < 8; ++nt) acc[nt] = (f32x4){0.f, 0.f, 0.f, 0.f};

#pragma unroll
    for (int c = 0; c < 4; ++c) {
        bf16x8 blv[8];
#pragma unroll
        for (int nt = 0; nt < 8; ++nt)
            blv[nt] = *(const bf16x8*)&Wlo[c * 512 + nt * 64 + lane];

        float v[8];
        *(float4*)&v[0] = ar[2 * c];
        *(float4*)&v[4] = ar[2 * c + 1];
        us8 hiu, lou;
#pragma unroll
        for (int j = 0; j < 8; ++j) {
            const unsigned short hb = f2bf(v[j]);
            hiu[j] = hb;
            lou[j] = f2bf(v[j] - bf2f(hb));
        }
        const bf16x8 ah = *(const bf16x8*)&hiu;
        const bf16x8 al = *(const bf16x8*)&lou;
#pragma unroll
        for (int nt = 0; nt < 8; ++nt) {
            const bf16x8 bh = *(const bf16x8*)&WH[c * 512 + nt * 64 + lane];
            acc[nt] = __builtin_amdgcn_mfma_f32_16x16x32_bf16(ah, bh, acc[nt], 0, 0, 0);
            acc[nt] = __builtin_amdgcn_mfma_f32_16x16x32_bf16(al, bh, acc[nt], 0, 0, 0);
            acc[nt] = __builtin_amdgcn_mfma_f32_16x16x32_bf16(ah, blv[nt], acc[nt], 0, 0, 0);
        }
    }

    // epilogue: C/D layout col = lane&15, row = (lane>>4)*4 + r (verified).
    // fp16 strip-major [4][NN][32]: strip = nt>>1, col = (nt&1)*16 + cl.
    const int q = lane >> 4, cl = lane & 15;
#pragma unroll
    for (int nt = 0; nt < 8; ++nt) {
        f16* o = h16 + (size_t)(nt >> 1) * ((size_t)NN * 32) + (nt & 1) * 16 + cl;
#pragma unroll
        for (int r = 0; r < 4; ++r)
            o[(size_t)(row0 + q * 4 + r) * 32] = (f16)acc[nt][r];
    }
}

// ---------------------------------------------------------------------------
// K2: per-partition exclusive scan over the NB_P block-counts (in place).
__global__ __launch_bounds__(256) void scan_blocks(int* __restrict__ cnt,
                                                   int* __restrict__ totals) {
    __shared__ int sw[256];
    const int p = blockIdx.x, tid = threadIdx.x;
    const int i0 = 2 * tid, i1 = 2 * tid + 1;
    const int a0 = (i0 < NB_P) ? cnt[p * NB_P + i0] : 0;
    const int a1 = (i1 < NB_P) ? cnt[p * NB_P + i1] : 0;
    const int pair = a0 + a1;
    sw[tid] = pair;
    __syncthreads();
    for (int off = 1; off < 256; off <<= 1) {
        int tv = (tid >= off) ? sw[tid - off] : 0;
        __syncthreads();
        if (tid >= off) sw[tid] += tv;
        __syncthreads();
    }
    const int excl = sw[tid] - pair;
    if (i0 < NB_P) cnt[p * NB_P + i0] = excl;
    if (i1 < NB_P) cnt[p * NB_P + i1] = excl + a0;
    if (tid == 255) totals[p] = sw[255];
}

// K3: scan partition totals -> binbase; also base[NN] = NE sentinel.
__global__ __launch_bounds__(256) void scan_parts(const int* __restrict__ totals,
                                                  int* __restrict__ binbase,
                                                  int* __restrict__ base) {
    __shared__ int sw[256];
    const int tid = threadIdx.x;
    const int v = (tid < NP) ? totals[tid] : 0;
    sw[tid] = v;
    __syncthreads();
    for (int off = 1; off < 256; off <<= 1) {
        int tv = (tid >= off) ? sw[tid - off] : 0;
        __syncthreads();
        if (tid >= off) sw[tid] += tv;
        __syncthreads();
    }
    if (tid < NP) binbase[tid] = sw[tid] - v;
    if (tid == NP - 1) {
        binbase[NP] = sw[tid];  // == NE
        base[NN] = sw[tid];
    }
}

// ---------------------------------------------------------------------------
// K4: scatter edges into partition-contiguous part[] (u64: w|row|colloc).
__global__ __launch_bounds__(256) void scatter_k(
    const int* __restrict__ row, const int* __restrict__ col,
    const float* __restrict__ w, const int* __restrict__ cnt,
    const int* __restrict__ binbase, u64* __restrict__ part) {
    __shared__ int bins[NP];
    __shared__ int off0[NP];
    const int b = blockIdx.x, t = threadIdx.x;
    for (int i = t; i < NP; i += 256) {
        bins[i] = 0;
        off0[i] = binbase[i] + cnt[i * NB_P + b];
    }
    __syncthreads();
    const int e0 = b * EPB + t;
#pragma unroll
    for (int s = 0; s < 8; ++s) {
        const int e = e0 + s * 256;
        if (e < NE) {
            const int c = col[e];
            const int p = c >> 8;
            const int lr = atomicAdd(&bins[p], 1);
            part[off0[p] + lr] = ((u64)__float_as_uint(w[e]) << 32) |
                                 ((u32)row[e] << 8) | (u32)(c & 255);
        }
    }
}

// ---------------------------------------------------------------------------
// K5: per-partition CSR finish: count + weighted degree -> dinv; scan ->
// base[node]; scatter sedge with PARTIAL norm w*dinv[col] (dinv[row] is
// applied inside the hops — removes the norm_k pass entirely).
__global__ __launch_bounds__(256) void csr_k(
    const u64* __restrict__ part, const int* __restrict__ binbase,
    int* __restrict__ base, float* __restrict__ dinv,
    int2* __restrict__ sedge) {
    __shared__ u32 cntL[256];
    __shared__ float wsL[256];   // weighted degree, then reused as dinv
    __shared__ int curL[256];
    __shared__ int sw[256];
    const int p = blockIdx.x, tid = threadIdx.x;
    const int eb = binbase[p], ee = binbase[p + 1];

    cntL[tid] = 0u;
    wsL[tid] = 0.f;
    __syncthreads();
    for (int e = eb + tid; e < ee; e += 256) {
        const u64 pk = part[e];
        const int cl = (int)(pk & 255u);
        atomicAdd(&cntL[cl], 1u);
        atomicAdd(&wsL[cl], __uint_as_float((u32)(pk >> 32)));
    }
    __syncthreads();

    const int node = p * 256 + tid;
    const float di = rsqrtf(1.0f + wsL[tid]);  // deg = 1 (self) + sum_in w
    const int myc = (int)cntL[tid];
    sw[tid] = myc;
    __syncthreads();
    for (int off = 1; off < 256; off <<= 1) {
        int tv = (tid >= off) ? sw[tid - off] : 0;
        __syncthreads();
        if (tid >= off) sw[tid] += tv;
        __syncthreads();
    }
    const int excl = sw[tid] - myc;
    if (node < NN) {
        dinv[node] = di;
        base[node] = eb + excl;
    }
    __syncthreads();
    wsL[tid] = di;
    curL[tid] = excl;
    __syncthreads();

    for (int e = eb + tid; e < ee; e += 256) {
        const u64 pk = part[e];
        const int cl = (int)(pk & 255u);
        const int r = (int)((pk >> 8) & 0xFFFFu);
        const float wv = __uint_as_float((u32)(pk >> 32));
        const int lr = atomicAdd(&curL[cl], 1);
        int2 ed;
        ed.x = r;
        ed.y = __float_as_int(wv * wsL[cl]);  // partial norm: w * dinv[col]
        sedge[eb + lr] = ed;
    }
}

// ---------------------------------------------------------------------------
// one hop: dst[n] = dinv[n]^2 * src[n] + dinv[n]*sum_in (w*dinv[r])*src[r]...
// actually sedge.y = w*dinv[c]; full norm = sedge.y * dinv[row] (in-loop).
// XCD-AFFINE strips: block b -> xcd x = b%8 -> strip x>>1, chunk parity x&1.
// Each XCD gathers ONLY from its own 3.2MB strip (fits its private 4MB L2),
// eliminating the 8x cross-XCD compulsory duplication that capped striping
// gains in rounds 1-2. 4-lane groups: 64 nodes/block, 64B gather per edge.
// OUTF=0: write fp16 strip-major; OUTF=1: write fp32 out.
// ---------------------------------------------------------------------------
template <int OUTF>
__global__ __launch_bounds__(256) void hop_kernel(
    const f16* __restrict__ src, f16* __restrict__ dst16,
    float* __restrict__ dstf, const int2* __restrict__ sedge,
    const int* __restrict__ base, const float* __restrict__ dinv) {
    const int xcd = blockIdx.x & 7;
    const int strip = xcd >> 1;
    const int chunk = (blockIdx.x >> 3) * 2 + (xcd & 1);
    const int node = chunk * 64 + (threadIdx.x >> 2);
    if (node >= NN) return;
    const int lo8 = (threadIdx.x & 3) * 8;
    const f16* hs = src + (size_t)strip * ((size_t)NN * 32) + lo8;

    const int b = base[node];
    const int k = base[node + 1] - b;

    float acc[8] = {0.f, 0.f, 0.f, 0.f, 0.f, 0.f, 0.f, 0.f};
#pragma unroll 4
    for (int j = 0; j < k; ++j) {
        const int2 ed = sedge[b + j];
        const f16x8 hv = *(const f16x8*)(hs + (size_t)ed.x * 32);
        const float nm = __int_as_float(ed.y) * dinv[ed.x];
#pragma unroll
        for (int i = 0; i < 8; ++i) acc[i] = fmaf(nm, (float)hv[i], acc[i]);
    }
    const float di = dinv[node];
    const float d2 = di * di;
    const f16x8 sv = *(const f16x8*)(hs + (size_t)node * 32);
#pragma unroll
    for (int i = 0; i < 8; ++i) acc[i] = fmaf(d2, (float)sv[i], acc[i]);

    if (OUTF) {
        float* o = dstf + (size_t)node * D + strip * 32 + lo8;
        *(float4*)&o[0] = make_float4(acc[0], acc[1], acc[2], acc[3]);
        *(float4*)&o[4] = make_float4(acc[4], acc[5], acc[6], acc[7]);
    } else {
        f16x8 ov;
#pragma unroll
        for (int i = 0; i < 8; ++i) ov[i] = (f16)acc[i];
        *(f16x8*)(dst16 + (size_t)strip * ((size_t)NN * 32) + (size_t)node * 32 + lo8) = ov;
    }
}

// ---------------------------------------------------------------------------
extern "C" void kernel_launch(void* const* d_in, const int* in_sizes, int n_in,
                              void* d_out, int out_size, void* d_ws,
                              size_t ws_size, hipStream_t stream) {
    const float* x  = (const float*)d_in[0];
    const int*   ei = (const int*)d_in[1];  // [2, NE]: row then col
    const float* w  = (const float*)d_in[2];
    const float* W  = (const float*)d_in[3];
    float* out = (float*)d_out;

    const int* row = ei;
    const int* col = ei + NE;

    // workspace carve-up (~31.1 MB)
    f16* h16a = (f16*)d_ws;                          // 4*NN*32 f16 = 12.8MB
    f16* h16b = h16a + (size_t)4 * NN * 32;          // 12.8MB
    u64* part = (u64*)h16b;                          // 4.8MB alias (dead before hop1)
    us8* Whi = (us8*)(h16b + (size_t)4 * NN * 32);   // 32KB
    us8* Wlo = Whi + 2048;                           // 32KB
    int* cnt = (int*)(Wlo + 2048);                   // NP*NB_P ints (230KB)
    int* totals = cnt + NP * NB_P;                   // NP
    int* binbase = totals + NP;                      // NP+1
    int* base = binbase + NP + 1;                    // NN+1
    float* dinv = (float*)(base + NN + 1);           // NN
    int2* sedge = (int2*)(dinv + NN);                // NE int2 = 4.8MB

    wprep<<<8, 256, 0, stream>>>(W, Whi, Wlo);
    gemm_count<<<NB_P + GGEMM, 256, 0, stream>>>(x, Whi, Wlo, h16a, col, cnt);
    scan_blocks<<<NP, 256, 0, stream>>>(cnt, totals);
    scan_parts<<<1, 256, 0, stream>>>(totals, binbase, base);
    scatter_k<<<NB_P, 256, 0, stream>>>(row, col, w, cnt, binbase, part);
    csr_k<<<NP, 256, 0, stream>>>(part, binbase, base, dinv, sedge);

    hop_kernel<0><<<GHOP, 256, 0, stream>>>(h16a, h16b, nullptr, sedge, base, dinv);
    hop_kernel<1><<<GHOP, 256, 0, stream>>>(h16b, nullptr, out, sedge, base, dinv);
}

// Round 7
// 106.184 us; speedup vs baseline: 1.1468x; 1.1468x over previous
//
#include <hip/hip_runtime.h>

typedef unsigned long long u64;
typedef unsigned int u32;
typedef _Float16 f16;

#define NN 50000
#define NE 600000
#define D  128
#define NWAVE 3125        // 50000 / 16 rows per GEMM wave
#define GGEMM 782         // ceil(3125 / 4 waves per block)
#define EPB 2048          // edges per partition-pass block (8 per thread)
#define NB_P 293          // ceil(600000 / 2048)
#define NP 196            // partitions: col >> 8 (256 nodes each)
#define NSTRIP 2          // hop strips: 64 fp16 cols = 128B = one full line
#define GS 1563           // hop blocks per strip: ceil(50000/32)

typedef __attribute__((ext_vector_type(8))) __bf16 bf16x8;
typedef __attribute__((ext_vector_type(8))) unsigned short us8;
typedef __attribute__((ext_vector_type(8))) f16 f16x8;
typedef __attribute__((ext_vector_type(4))) float f32x4;

__device__ __forceinline__ unsigned short f2bf(float f) {
    u32 u = __float_as_uint(f);
    return (unsigned short)((u + 0x7FFFu + ((u >> 16) & 1u)) >> 16);  // RNE
}
__device__ __forceinline__ float bf2f(unsigned short h) {
    return __uint_as_float((u32)h << 16);
}

// ---------------------------------------------------------------------------
// Fused kernel. Blocks [0, NB_P): partition COUNT — per-block 196-bin LDS
//   histogram of col>>8; writes cnt[p][b] (fully overwrites -> no memset).
//   Block 0 also zeroes the scan ticket.
// Blocks [NB_P, ...): GEMM h16 = fp16(x @ W^T), split-bf16 MFMA. W is
//   converted in-block (fp32 from L2 -> frag-order hi/lo bf16 in 64KB LDS),
//   removing the wprep launch and making all B-operand reads LDS.
//   Output fp16 strip-major [2][NN][64].
// ---------------------------------------------------------------------------
__global__ __launch_bounds__(256) void gemm_count(
    const float* __restrict__ x, const float* __restrict__ W,
    f16* __restrict__ h16, const int* __restrict__ col,
    int* __restrict__ cnt, u32* __restrict__ done) {
    const int t = threadIdx.x;
    __shared__ us8 WH[2048];  // 32 KB hi (GEMM); reused as bins (count role)
    __shared__ us8 WL[2048];  // 32 KB lo

    if (blockIdx.x < NB_P) {
        // ---- partition-count role ----
        if (blockIdx.x == 0 && t == 0) *done = 0u;  // ticket for scan_fused
        int* bins = (int*)WH;
        for (int i = t; i < NP; i += 256) bins[i] = 0;
        __syncthreads();
        const int e0 = blockIdx.x * EPB + t;
#pragma unroll
        for (int s = 0; s < 8; ++s) {
            const int e = e0 + s * 256;
            if (e < NE) atomicAdd(&bins[col[e] >> 8], 1);
        }
        __syncthreads();
        for (int i = t; i < NP; i += 256)
            cnt[i * NB_P + blockIdx.x] = bins[i];
        return;
    }

    // ---- GEMM role ----
    const int g = (blockIdx.x - NB_P) * 4 + (t >> 6);
    const int lane = t & 63;
    const int gc = (g < NWAVE) ? g : (NWAVE - 1);
    const int row0 = gc * 16;

    // issue all 8 cold x loads up front (128B/lane, 16 full lines per wave)
    const float* px = x + (size_t)(row0 + (lane & 15)) * D + (lane >> 4) * 8;
    float4 ar[8];
#pragma unroll
    for (int c = 0; c < 4; ++c) {
        ar[2 * c]     = *(const float4*)(px + c * 32);
        ar[2 * c + 1] = *(const float4*)(px + c * 32 + 4);
    }

    // stage + split W -> LDS (frag-order) while x loads are in flight.
    // chunk i = kc4*512 + nt*64 + ln holds W[nt*16+(ln&15)][kc4*32+(ln>>4)*8+e]
#pragma unroll
    for (int s = 0; s < 8; ++s) {
        const int i = s * 256 + t;
        const int ln = i & 63, nt = (i >> 6) & 7, kc4 = i >> 9;
        const float* p =
            W + (size_t)(nt * 16 + (ln & 15)) * D + kc4 * 32 + (ln >> 4) * 8;
        float v[8];
        *(float4*)&v[0] = *(const float4*)p;
        *(float4*)&v[4] = *(const float4*)(p + 4);
        us8 hi, lo;
#pragma unroll
        for (int j = 0; j < 8; ++j) {
            const unsigned short hb = f2bf(v[j]);
            hi[j] = hb;
            lo[j] = f2bf(v[j] - bf2f(hb));
        }
        WH[i] = hi;
        WL[i] = lo;
    }
    __syncthreads();
    if (g >= NWAVE) return;

    f32x4 acc[8];
#pragma unroll
    for (int nt = 0; nt < 8; ++nt) acc[nt] = (f32x4){0.f, 0.f, 0.f, 0.f};

#pragma unroll
    for (int c = 0; c < 4; ++c) {
        float v[8];
        *(float4*)&v[0] = ar[2 * c];
        *(float4*)&v[4] = ar[2 * c + 1];
        us8 hiu, lou;
#pragma unroll
        for (int j = 0; j < 8; ++j) {
            const unsigned short hb = f2bf(v[j]);
            hiu[j] = hb;
            lou[j] = f2bf(v[j] - bf2f(hb));
        }
        const bf16x8 ah = *(const bf16x8*)&hiu;
        const bf16x8 al = *(const bf16x8*)&lou;
#pragma unroll
        for (int nt = 0; nt < 8; ++nt) {
            const bf16x8 bh = *(const bf16x8*)&WH[c * 512 + nt * 64 + lane];
            const bf16x8 bl = *(const bf16x8*)&WL[c * 512 + nt * 64 + lane];
            acc[nt] = __builtin_amdgcn_mfma_f32_16x16x32_bf16(ah, bh, acc[nt], 0, 0, 0);
            acc[nt] = __builtin_amdgcn_mfma_f32_16x16x32_bf16(al, bh, acc[nt], 0, 0, 0);
            acc[nt] = __builtin_amdgcn_mfma_f32_16x16x32_bf16(ah, bl, acc[nt], 0, 0, 0);
        }
    }

    // epilogue: C/D layout col = lane&15, row = (lane>>4)*4 + r (verified).
    // fp16 strip-major [2][NN][64]: strip = nt>>2, col = (nt&3)*16 + cl.
    const int q = lane >> 4, cl = lane & 15;
#pragma unroll
    for (int nt = 0; nt < 8; ++nt) {
        f16* o = h16 + (size_t)(nt >> 2) * ((size_t)NN * 64) + (nt & 3) * 16 + cl;
#pragma unroll
        for (int r = 0; r < 4; ++r)
            o[(size_t)(row0 + q * 4 + r) * 64] = (f16)acc[nt][r];
    }
}

// ---------------------------------------------------------------------------
// scan_fused: per-partition exclusive scan over NB_P block-counts (in place)
// + last-block-done partition-totals scan (replaces scan_blocks+scan_parts).
// Cross-XCD safety: totals published via device-scope atomicExch; the last
// block (ticket == NP-1) reads them back via atomic add-0.
__global__ __launch_bounds__(256) void scan_fused(
    int* __restrict__ cnt, int* __restrict__ totals,
    int* __restrict__ binbase, int* __restrict__ base,
    u32* __restrict__ done) {
    __shared__ int sw[256];
    __shared__ u32 ticket;
    const int p = blockIdx.x, tid = threadIdx.x;
    const int i0 = 2 * tid, i1 = 2 * tid + 1;
    const int a0 = (i0 < NB_P) ? cnt[p * NB_P + i0] : 0;
    const int a1 = (i1 < NB_P) ? cnt[p * NB_P + i1] : 0;
    const int pair = a0 + a1;
    sw[tid] = pair;
    __syncthreads();
    for (int off = 1; off < 256; off <<= 1) {
        int tv = (tid >= off) ? sw[tid - off] : 0;
        __syncthreads();
        if (tid >= off) sw[tid] += tv;
        __syncthreads();
    }
    const int excl = sw[tid] - pair;
    if (i0 < NB_P) cnt[p * NB_P + i0] = excl;
    if (i1 < NB_P) cnt[p * NB_P + i1] = excl + a0;
    if (tid == 0) {
        atomicExch(&totals[p], sw[255]);  // device-scope publish
        __threadfence();
        ticket = atomicAdd(done, 1u);
    }
    __syncthreads();
    if (ticket != NP - 1) return;

    // last block: scan partition totals -> binbase; base[NN] sentinel.
    const int v = (tid < NP) ? atomicAdd(&totals[tid], 0) : 0;
    sw[tid] = v;
    __syncthreads();
    for (int off = 1; off < 256; off <<= 1) {
        int tv = (tid >= off) ? sw[tid - off] : 0;
        __syncthreads();
        if (tid >= off) sw[tid] += tv;
        __syncthreads();
    }
    if (tid < NP) binbase[tid] = sw[tid] - v;
    if (tid == NP - 1) {
        binbase[NP] = sw[tid];  // == NE
        base[NN] = sw[tid];
    }
}

// ---------------------------------------------------------------------------
// scatter edges into partition-contiguous part[] (u64: w|row|colloc).
__global__ __launch_bounds__(256) void scatter_k(
    const int* __restrict__ row, const int* __restrict__ col,
    const float* __restrict__ w, const int* __restrict__ cnt,
    const int* __restrict__ binbase, u64* __restrict__ part) {
    __shared__ int bins[NP];
    __shared__ int off0[NP];
    const int b = blockIdx.x, t = threadIdx.x;
    for (int i = t; i < NP; i += 256) {
        bins[i] = 0;
        off0[i] = binbase[i] + cnt[i * NB_P + b];
    }
    __syncthreads();
    const int e0 = b * EPB + t;
#pragma unroll
    for (int s = 0; s < 8; ++s) {
        const int e = e0 + s * 256;
        if (e < NE) {
            const int c = col[e];
            const int p = c >> 8;
            const int lr = atomicAdd(&bins[p], 1);
            part[off0[p] + lr] = ((u64)__float_as_uint(w[e]) << 32) |
                                 ((u32)row[e] << 8) | (u32)(c & 255);
        }
    }
}

// ---------------------------------------------------------------------------
// per-partition CSR finish: count + weighted degree -> dinv; scan ->
// base[node]; scatter sedge with PARTIAL norm w*dinv[col] (dinv[row] is
// applied inside the hops).
__global__ __launch_bounds__(256) void csr_k(
    const u64* __restrict__ part, const int* __restrict__ binbase,
    int* __restrict__ base, float* __restrict__ dinv,
    int2* __restrict__ sedge) {
    __shared__ u32 cntL[256];
    __shared__ float wsL[256];   // weighted degree, then reused as dinv
    __shared__ int curL[256];
    __shared__ int sw[256];
    const int p = blockIdx.x, tid = threadIdx.x;
    const int eb = binbase[p], ee = binbase[p + 1];

    cntL[tid] = 0u;
    wsL[tid] = 0.f;
    __syncthreads();
    for (int e = eb + tid; e < ee; e += 256) {
        const u64 pk = part[e];
        const int cl = (int)(pk & 255u);
        atomicAdd(&cntL[cl], 1u);
        atomicAdd(&wsL[cl], __uint_as_float((u32)(pk >> 32)));
    }
    __syncthreads();

    const int node = p * 256 + tid;
    const float di = rsqrtf(1.0f + wsL[tid]);  // deg = 1 (self) + sum_in w
    const int myc = (int)cntL[tid];
    sw[tid] = myc;
    __syncthreads();
    for (int off = 1; off < 256; off <<= 1) {
        int tv = (tid >= off) ? sw[tid - off] : 0;
        __syncthreads();
        if (tid >= off) sw[tid] += tv;
        __syncthreads();
    }
    const int excl = sw[tid] - myc;
    if (node < NN) {
        dinv[node] = di;
        base[node] = eb + excl;
    }
    __syncthreads();
    wsL[tid] = di;
    curL[tid] = excl;
    __syncthreads();

    for (int e = eb + tid; e < ee; e += 256) {
        const u64 pk = part[e];
        const int cl = (int)(pk & 255u);
        const int r = (int)((pk >> 8) & 0xFFFFu);
        const float wv = __uint_as_float((u32)(pk >> 32));
        const int lr = atomicAdd(&curL[cl], 1);
        int2 ed;
        ed.x = r;
        ed.y = __float_as_int(wv * wsL[cl]);  // partial norm: w * dinv[col]
        sedge[eb + lr] = ed;
    }
}

// ---------------------------------------------------------------------------
// one hop: dst[n] = dinv[n]^2 * src[n] + sum_in (w*dinv[r]*dinv[n]) * src[r]
// sedge.y = w*dinv[col]; the dinv[row] factor is applied in-loop (broadcast
// load from the 200KB L2-resident dinv table). fp16 strip-major [2][NN][64]:
// each gather = exactly one 128B line (the measured-optimal granularity;
// round 6's 64B granule halved line utilization and regressed).
// 8-lane groups (fp16x8); blockIdx.y = strip.
// OUTF=0: write fp16 strip-major; OUTF=1: write fp32 out.
// ---------------------------------------------------------------------------
template <int OUTF>
__global__ __launch_bounds__(256) void hop_kernel(
    const f16* __restrict__ src, f16* __restrict__ dst16,
    float* __restrict__ dstf, const int2* __restrict__ sedge,
    const int* __restrict__ base, const float* __restrict__ dinv) {
    const int node = blockIdx.x * 32 + (threadIdx.x >> 3);
    if (node >= NN) return;
    const int strip = blockIdx.y;
    const int lo8 = (threadIdx.x & 7) * 8;
    const f16* hs = src + (size_t)strip * ((size_t)NN * 64) + lo8;

    const int b = base[node];
    const int k = base[node + 1] - b;

    float acc[8] = {0.f, 0.f, 0.f, 0.f, 0.f, 0.f, 0.f, 0.f};
#pragma unroll 4
    for (int j = 0; j < k; ++j) {
        const int2 ed = sedge[b + j];
        const f16x8 hv = *(const f16x8*)(hs + (size_t)ed.x * 64);
        const float nm = __int_as_float(ed.y) * dinv[ed.x];
#pragma unroll
        for (int i = 0; i < 8; ++i) acc[i] = fmaf(nm, (float)hv[i], acc[i]);
    }
    const float di = dinv[node];
    const float d2 = di * di;
    const f16x8 sv = *(const f16x8*)(hs + (size_t)node * 64);
#pragma unroll
    for (int i = 0; i < 8; ++i) acc[i] = fmaf(d2, (float)sv[i], acc[i]);

    if (OUTF) {
        float* o = dstf + (size_t)node * D + strip * 64 + lo8;
        *(float4*)&o[0] = make_float4(acc[0], acc[1], acc[2], acc[3]);
        *(float4*)&o[4] = make_float4(acc[4], acc[5], acc[6], acc[7]);
    } else {
        f16x8 ov;
#pragma unroll
        for (int i = 0; i < 8; ++i) ov[i] = (f16)acc[i];
        *(f16x8*)(dst16 + (size_t)strip * ((size_t)NN * 64) + (size_t)node * 64 + lo8) = ov;
    }
}

// ---------------------------------------------------------------------------
extern "C" void kernel_launch(void* const* d_in, const int* in_sizes, int n_in,
                              void* d_out, int out_size, void* d_ws,
                              size_t ws_size, hipStream_t stream) {
    const float* x  = (const float*)d_in[0];
    const int*   ei = (const int*)d_in[1];  // [2, NE]: row then col
    const float* w  = (const float*)d_in[2];
    const float* W  = (const float*)d_in[3];
    float* out = (float*)d_out;

    const int* row = ei;
    const int* col = ei + NE;

    // workspace carve-up (~31 MB)
    f16* h16a = (f16*)d_ws;                          // 2*NN*64 f16 = 12.8MB
    f16* h16b = h16a + (size_t)2 * NN * 64;          // 12.8MB
    u64* part = (u64*)h16b;                          // 4.8MB alias (dead before hop1)
    int* cnt = (int*)(h16b + (size_t)2 * NN * 64);   // NP*NB_P ints (230KB)
    int* totals = cnt + NP * NB_P;                   // NP
    u32* done = (u32*)(totals + NP);                 // 1
    int* binbase = (int*)(done + 1);                 // NP+1
    int* base = binbase + NP + 1;                    // NN+1
    float* dinv = (float*)(base + NN + 1);           // NN
    int2* sedge = (int2*)(dinv + NN);                // NE int2 = 4.8MB

    gemm_count<<<NB_P + GGEMM, 256, 0, stream>>>(x, W, h16a, col, cnt, done);
    scan_fused<<<NP, 256, 0, stream>>>(cnt, totals, binbase, base, done);
    scatter_k<<<NB_P, 256, 0, stream>>>(row, col, w, cnt, binbase, part);
    csr_k<<<NP, 256, 0, stream>>>(part, binbase, base, dinv, sedge);

    hop_kernel<0><<<dim3(GS, NSTRIP), 256, 0, stream>>>(h16a, h16b, nullptr,
                                                        sedge, base, dinv);
    hop_kernel<1><<<dim3(GS, NSTRIP), 256, 0, stream>>>(h16b, nullptr, out,
                                                        sedge, base, dinv);
}